// Round 4
// baseline (780.012 us; speedup 1.0000x reference)
//
#include <hip/hip_runtime.h>
#include <hip/hip_bf16.h>
#include <math.h>

// ModelParallelSoftmaxLoss: loss = mean(logsumexp(x@W^T + b) - (x@W^T+b)[lb])
// N=4096, D=512, V=100000.
// R10: barrier-free wave-private pipeline. R9 was convergence-bound: per-phase
//      wall 3437 cy vs 1100 MFMA + 770 LDS + VALU — all pipes <33%; the block
//      barrier (forced by cooperative staging: wave stages groups it doesn't
//      consume) serialized wave skew every phase at only 2 waves/SIMD.
//      (a) each wave stages exactly its own 4 col-groups into its own 2x8KB
//          LDS buffers -> NO barriers in the main loop; waves free-run and
//          co-scheduled waves fill each other's latency bubbles (m114).
//      (b) per-wave counted pipeline: depth 2, WAITV(8) per K-step (8 gloads
//          per stage), lgkmcnt(0) before WAR overwrite, tail peel 8,8,8,0.
//      (c) B bytes staged 2x per block (rh duplicate): LDS writes 32KB/blk-Kstep
//          (~58 B/cy < 128 peak), 2x L2 reads (swizzle keeps them L2-local).
//      (d) aux: tgt merged into cvt (prep_kernel) — one fewer launch.
//      Retained: Aa[4][4] in regs (compile-time ks), log2e folded into x fp8,
//      C=0 first-MFMA, bias in LDS, setprio, bijective XCD swizzle.

#define N_ROWS 4096
#define DIM    512              // elements per row == bytes per row in fp8
#define VOCAB  100000
#define NTILES 782              // ceil(100000/128)
#define VPAD   (NTILES * 128)   // 100096
#define SPLITS 32
#define TPS    25               // ceil(782/32)
#define XELEMS (N_ROWS * DIM)           // 2097152
#define WVALID ((size_t)VOCAB * DIM)    // 51200000
#define WBYTES ((size_t)VPAD * DIM)     // 51249152
#define TILEB  (128 * DIM)              // 65536 B: one 128-col V-tile of W(fp8)
#define CVT_BLOCKS 13024

#define LOG2E 1.44269504088896340736f

typedef __attribute__((ext_vector_type(4))) int   i32x4;
typedef __attribute__((ext_vector_type(8))) int   i32x8;
typedef __attribute__((ext_vector_type(4))) float f32x4;

// ---------------- helpers ----------------

__device__ __forceinline__ void gload_lds16(const char* g, char* l) {
  // async global->LDS, 16B/lane; LDS dest = wave-uniform base + lane*16
  __builtin_amdgcn_global_load_lds(
      (const __attribute__((address_space(1))) unsigned int*)g,
      (__attribute__((address_space(3))) unsigned int*)l, 16, 0, 0);
}

__device__ __forceinline__ int pack4_fp8(float4 f, float sc) {
  int p = __builtin_amdgcn_cvt_pk_fp8_f32(f.x * sc, f.y * sc, 0, false);
  p = __builtin_amdgcn_cvt_pk_fp8_f32(f.z * sc, f.w * sc, p, true);
  return p;
}

// read one 32B fragment stored fragment-order: lo at base, hi at base+1024
__device__ __forceinline__ i32x8 frag32(const char* base) {
  i32x4 lo = *(const i32x4*)(base);
  i32x4 hi = *(const i32x4*)(base + 1024);
  return (i32x8){lo.x, lo.y, lo.z, lo.w, hi.x, hi.y, hi.z, hi.w};
}

// ---------------- prep: fused cvt (x*log2e, W*32 -> fp8) + exact fp32 tgt ----------------

__global__ __launch_bounds__(256) void prep_kernel(const float* __restrict__ x,
                                                   const float* __restrict__ W,
                                                   char* __restrict__ out8,
                                                   const int* __restrict__ lb,
                                                   const float* __restrict__ bias,
                                                   float* __restrict__ tgt) {
  if (blockIdx.x < CVT_BLOCKS) {
    // ---- cvt part: grid 13024 x 256 x 16B covers x_fp8 | W_fp8 | pad exactly
    const size_t e = ((size_t)blockIdx.x * 256 + threadIdx.x) * 16;
    int4 o;
    if (e < (size_t)XELEMS) {
      // x pre-scaled by log2(e): GEMM yields logits*log2e -> epilogue is raw exp2.
      const float4* s = (const float4*)(x + e);
      o.x = pack4_fp8(s[0], LOG2E); o.y = pack4_fp8(s[1], LOG2E);
      o.z = pack4_fp8(s[2], LOG2E); o.w = pack4_fp8(s[3], LOG2E);
    } else if (e - XELEMS < WVALID) {
      const float4* s = (const float4*)(W + (e - XELEMS));
      o.x = pack4_fp8(s[0], 32.f); o.y = pack4_fp8(s[1], 32.f);
      o.z = pack4_fp8(s[2], 32.f); o.w = pack4_fp8(s[3], 32.f);
    } else {
      o.x = 0; o.y = 0; o.z = 0; o.w = 0;   // vocab pad rows (also masked via -inf bias)
    }
    *(int4*)(out8 + e) = o;
  } else {
    // ---- tgt part: 1024 blocks x 4 waves -> 4096 rows; exact fp32 dot
    const int wv = threadIdx.x >> 6;
    const int lane = threadIdx.x & 63;
    const int row = (blockIdx.x - CVT_BLOCKS) * 4 + wv;
    const int t = lb[row];
    const float* xr = x + (size_t)row * DIM;
    const float* wr = W + (size_t)t * DIM;
    float s = 0.f;
#pragma unroll
    for (int i = 0; i < 8; ++i) s += xr[lane + i * 64] * wr[lane + i * 64];
#pragma unroll
    for (int m = 32; m; m >>= 1) s += __shfl_xor(s, m);
    if (lane == 0) tgt[row] = s + bias[t];
  }
}

// ---------------- fused MX-fp8 GEMM + sum-exp ----------------
// grid: 1024 = 32 m-tiles x 32 V-splits. block: 4 waves = 2 row-halves (rh) x
// 2 col-halves (ch). Wave owns 64 rows (4 frags of 16) x 64 cols (4 groups of
// 16). K=128 MFMA, 4 K-steps over D=512.
// A frag (regs, 128 VGPR): lane(fr,fq) = row fr, k-bytes fq*32..+31 per K-window.
// Wave-private B LDS: 2 buffers x 8KB; buffer = ks&1; group gg (0..3 = global
// group 4ch+gg) at gg*2048; slot half*1024 + lane*16 = row 16(4ch+gg)+fr,
// k-bytes fq*32+half*16..+15. Staged by the SAME wave that reads it -> no
// cross-wave hazards, no barriers. Depth-2 counted pipeline per wave:
//   K-step u: WAITV(8) [stage(u) landed, stage(u+1) in flight] -> 8 ds_read
//   -> lgkmcnt(0) [WAR] -> stage(u+2) into the just-freed buffer -> 16 MFMA.
// Scales: A identity (127, log2e folded into x fp8); B 2^-5 (122).

__global__ __launch_bounds__(256, 2) void lse_kernel(const char* __restrict__ xb,
                                                     const char* __restrict__ wb,
                                                     const float* __restrict__ bias,
                                                     float* __restrict__ spart) {
  __shared__ __align__(16) char ldsB[4][2][8192];   // [wave][buf] 64KB total
  __shared__ float ldsBias[TPS * 128];              // 12.8KB bias (log2e-scaled)

  // Bijective XCD swizzle: one XCD's co-resident blocks cover splits {2x,2x+1}
  // x all 32 m-tiles -> W slices (3.2MB) fit the 4MB per-XCD L2.
  const int d = blockIdx.x;
  const int s     = 2 * (d & 7) + ((d >> 3) & 1) + 16 * (d >> 9);
  const int mtile = (d >> 4) & 31;

  const int m0 = mtile * 128;
  const int t0 = s * TPS;
  const int t1 = (t0 + TPS < NTILES) ? (t0 + TPS) : NTILES;
  const int NT = t1 - t0;                 // 25, or 7 on the last split

  const int tid  = threadIdx.x;
  const int lane = tid & 63;
  const int wv   = tid >> 6;
  const int rh   = wv >> 1;          // row-half (64 rows)
  const int ch   = wv & 1;           // col-half (4 of the 8 col-groups)
  const int fr   = lane & 15;        // frag row (A) / col (B,C); staging row-in-group
  const int fq   = lane >> 4;        // frag quad; staging k-chunk

  // ---- load A fragments into registers (128 VGPRs): 4 row-frags x 4 ksteps ----
  i32x8 Aa[4][4];
  {
    const char* ax = xb + (size_t)(m0 + 64 * rh + fr) * DIM + fq * 32;
#pragma unroll
    for (int rf = 0; rf < 4; ++rf)
#pragma unroll
      for (int ks = 0; ks < 4; ++ks) {
        const char* p = ax + rf * (16 * DIM) + ks * 128;
        i32x4 lo = *(const i32x4*)p;
        i32x4 hi = *(const i32x4*)(p + 16);
        Aa[rf][ks] = (i32x8){lo.x, lo.y, lo.z, lo.w, hi.x, hi.y, hi.z, hi.w};
      }
  }

  // ---- stage this split's bias into LDS ----
  for (int c = tid; c < NT * 128; c += 256) {
    const int col = t0 * 128 + c;
    ldsBias[c] = (col < VOCAB) ? bias[col] * LOG2E : -INFINITY;
  }
  __syncthreads();                                   // bias visible; full drain
  asm volatile("s_waitcnt vmcnt(0)" ::: "memory");   // counted-math clean slate
  __builtin_amdgcn_sched_barrier(0);

  // wave-private staging: this wave's 4 col-groups (global 4ch..4ch+3), 8 gloads
  char* const myB  = &ldsB[wv][0][0];
  char* const buf0 = myB;
  char* const buf1 = myB + 8192;
  const size_t rowBase = (size_t)(64 * ch + fr) * DIM + fq * 32;

  auto stageK = [&](const char* tileSrc, int ks, char* dst) {
#pragma unroll
    for (int gg = 0; gg < 4; ++gg) {
      const char* src = tileSrc + rowBase + (size_t)(16 * gg) * DIM + ks * 128;
      gload_lds16(src,      dst + gg * 2048);
      gload_lds16(src + 16, dst + gg * 2048 + 1024);
    }
  };

  float S[4][4];
#pragma unroll
  for (int rf = 0; rf < 4; ++rf)
#pragma unroll
    for (int r = 0; r < 4; ++r) S[rf][r] = 0.f;

  f32x4 acc[4][4];   // [row-frag][col-frag]; C=0 at each tile's ks0

// one K-step: wait own stage(u), read 4 frag32, WAR-fence, stage(u+2), 16 MFMA
#define K_STEP(ksC, FIRSTF, WAITIMM, STAGE_EXPR)                              \
  {                                                                           \
    asm volatile("s_waitcnt vmcnt(" #WAITIMM ")" ::: "memory");               \
    __builtin_amdgcn_sched_barrier(0);                                        \
    const char* fb_ = myB + ((ksC) & 1) * 8192 + lane * 16;                   \
    const i32x8 b0_ = frag32(fb_);                                            \
    const i32x8 b1_ = frag32(fb_ + 2048);                                     \
    const i32x8 b2_ = frag32(fb_ + 4096);                                     \
    const i32x8 b3_ = frag32(fb_ + 6144);                                     \
    asm volatile("s_waitcnt lgkmcnt(0)" ::: "memory");                        \
    __builtin_amdgcn_sched_barrier(0);                                        \
    STAGE_EXPR;                                                               \
    __builtin_amdgcn_s_setprio(1);                                            \
    _Pragma("unroll")                                                         \
    for (int rf_ = 0; rf_ < 4; ++rf_) {                                       \
      acc[rf_][0] = __builtin_amdgcn_mfma_scale_f32_16x16x128_f8f6f4(         \
          Aa[rf_][ksC], b0_,                                                  \
          (FIRSTF) ? (f32x4){0.f, 0.f, 0.f, 0.f} : acc[rf_][0],               \
          0, 0, 0, 127, 0, 122);                                              \
      acc[rf_][1] = __builtin_amdgcn_mfma_scale_f32_16x16x128_f8f6f4(         \
          Aa[rf_][ksC], b1_,                                                  \
          (FIRSTF) ? (f32x4){0.f, 0.f, 0.f, 0.f} : acc[rf_][1],               \
          0, 0, 0, 127, 0, 122);                                              \
      acc[rf_][2] = __builtin_amdgcn_mfma_scale_f32_16x16x128_f8f6f4(         \
          Aa[rf_][ksC], b2_,                                                  \
          (FIRSTF) ? (f32x4){0.f, 0.f, 0.f, 0.f} : acc[rf_][2],               \
          0, 0, 0, 127, 0, 122);                                              \
      acc[rf_][3] = __builtin_amdgcn_mfma_scale_f32_16x16x128_f8f6f4(         \
          Aa[rf_][ksC], b3_,                                                  \
          (FIRSTF) ? (f32x4){0.f, 0.f, 0.f, 0.f} : acc[rf_][3],               \
          0, 0, 0, 127, 0, 122);                                              \
    }                                                                         \
    __builtin_amdgcn_s_setprio(0);                                            \
  }

  auto epilogue = [&](int ti) {
    // C/D (16x16): col = (t0+ti)*128 + 64ch + 16c + fr, row = m0+64rh+16rf+4fq+r
    const float* bT = &ldsBias[ti * 128 + 64 * ch];
    float badd[4];
#pragma unroll
    for (int c = 0; c < 4; ++c) badd[c] = bT[16 * c + fr];
#pragma unroll
    for (int rf = 0; rf < 4; ++rf)
#pragma unroll
      for (int r = 0; r < 4; ++r) {
        float sum = 0.f;
#pragma unroll
        for (int c = 0; c < 4; ++c)
          sum += __builtin_amdgcn_exp2f(acc[rf][c][r] + badd[c]);
        S[rf][r] += sum;
      }
  };

  const char* wt = wb + (size_t)t0 * TILEB;

  // prologue: K-steps 0,1 of tile t0 in flight (16 loads outstanding)
  stageK(wt, 0, buf0);
  stageK(wt, 1, buf1);

  for (int tt = t0; tt < t1 - 1; ++tt, wt += TILEB) {
    K_STEP(0, true,  8, stageK(wt, 2, buf0))
    K_STEP(1, false, 8, stageK(wt, 3, buf1))
    K_STEP(2, false, 8, stageK(wt + TILEB, 0, buf0))
    K_STEP(3, false, 8, stageK(wt + TILEB, 1, buf1))
    epilogue(tt - t0);   // free-running: no barrier; other waves keep pipes fed
  }

  // last tile: no next-tile stages; waits 8,8,8,0
  {
    K_STEP(0, true,  8, stageK(wt, 2, buf0))
    K_STEP(1, false, 8, stageK(wt, 3, buf1))
    K_STEP(2, false, 8, (void)0)
    K_STEP(3, false, 0, (void)0)
    epilogue(NT - 1);
  }
#undef K_STEP

  // ---- cross-wave (col-half) reduction: ch=1 dumps S, ch=0 accumulates ----
  __syncthreads();                       // first barrier since bias; ldsB free
  float* sc = (float*)ldsB;              // stride 20 floats: bank-spread, x4-aligned
  if (ch == 1) {
    float* base = sc + (size_t)(rh * 64 + lane) * 20;
#pragma unroll
    for (int rf = 0; rf < 4; ++rf)
      *(float4*)(base + rf * 4) = (float4){S[rf][0], S[rf][1], S[rf][2], S[rf][3]};
  }
  __syncthreads();
  if (ch == 0) {
    const float* base = sc + (size_t)(rh * 64 + lane) * 20;
#pragma unroll
    for (int rf = 0; rf < 4; ++rf) {
      const float4 v = *(const float4*)(base + rf * 4);
      S[rf][0] += v.x; S[rf][1] += v.y; S[rf][2] += v.z; S[rf][3] += v.w;
    }
    // reduce over the 16 fr-lanes sharing each row, write partials
#pragma unroll
    for (int rf = 0; rf < 4; ++rf)
#pragma unroll
      for (int r = 0; r < 4; ++r) {
        float v = S[rf][r];
        v += __shfl_xor(v, 1);
        v += __shfl_xor(v, 2);
        v += __shfl_xor(v, 4);
        v += __shfl_xor(v, 8);
        if (fr == 0) {
          const int row = m0 + 64 * rh + 16 * rf + 4 * fq + r;
          spart[(size_t)row * SPLITS + s] = v;
        }
      }
  }
}

// ---------------- combine: loss = mean(log(sum_s S_part) - tgt), single block ----------------

__global__ __launch_bounds__(256) void combine_kernel(const float* __restrict__ spart,
                                                      const float* __restrict__ tgt,
                                                      float* __restrict__ out) {
  __shared__ float red[256];
  float local = 0.f;
  for (int r = threadIdx.x; r < N_ROWS; r += 256) {
    const float4* sp = (const float4*)(spart + (size_t)r * SPLITS);
    float st = 0.f;
#pragma unroll
    for (int i = 0; i < 8; ++i) { float4 v = sp[i]; st += (v.x + v.y) + (v.z + v.w); }
    local += __logf(st) - tgt[r];
  }
  red[threadIdx.x] = local;
  __syncthreads();
  for (int step = 128; step; step >>= 1) {
    if (threadIdx.x < step) red[threadIdx.x] += red[threadIdx.x + step];
    __syncthreads();
  }
  if (threadIdx.x == 0) out[0] = red[0] * (1.0f / (float)N_ROWS);
}

// ---------------- launch ----------------
// ws: x_fp8 [4096][512]B @0 | W_fp8 [100096][512]B | S_part [4096][32] f32 | tgt [4096] f32

extern "C" void kernel_launch(void* const* d_in, const int* in_sizes, int n_in,
                              void* d_out, int out_size, void* d_ws, size_t ws_size,
                              hipStream_t stream) {
  const float* x  = (const float*)d_in[0];
  const int*   lb = (const int*)d_in[1];
  const float* W  = (const float*)d_in[2];
  const float* b  = (const float*)d_in[3];
  float* out = (float*)d_out;

  char* ws = (char*)d_ws;
  const size_t OFF_W   = (size_t)XELEMS;          // 2097152
  const size_t OFF_SP  = OFF_W + WBYTES;          // 53346304
  const size_t OFF_TGT = OFF_SP + (size_t)N_ROWS * SPLITS * 4;
  char*  xb    = ws;
  char*  wb    = ws + OFF_W;
  float* spart = (float*)(ws + OFF_SP);
  float* tgt   = (float*)(ws + OFF_TGT);

  prep_kernel<<<CVT_BLOCKS + 1024, 256, 0, stream>>>(x, W, ws, lb, b, tgt);
  lse_kernel<<<1024, 256, 0, stream>>>(xb, wb, b, spart);
  combine_kernel<<<1, 256, 0, stream>>>(spart, tgt, out);
}

// Round 5
// 672.891 us; speedup vs baseline: 1.1592x; 1.1592x over previous
//
#include <hip/hip_runtime.h>
#include <hip/hip_bf16.h>
#include <math.h>

// ModelParallelSoftmaxLoss: loss = mean(logsumexp(x@W^T + b) - (x@W^T+b)[lb])
// N=4096, D=512, V=100000.
// R11: two fixes from R10's post-mortem.
//      (1) lse spill fix: R10's WRITE_SIZE 6->139MB = scratch (one dword
//          spill/thread/K-step; 32 B-frag VGPRs live across stage tipped the
//          256/wave budget). Restore R9's one-frag-at-a-time B read inside the
//          MFMA loop; keep the (untested) barrier-free wave-private pipeline:
//          each wave stages exactly the 4 col-groups it consumes into its own
//          2x8KB buffers; depth-2 counted vmcnt(8); lgkmcnt(0) WAR fence
//          before re-staging; NO block barriers in the main loop.
//      (2) cvt coalescing fix: old cvt read 4 float4/thread (64B/lane ->
//          consecutive lanes 64B apart: every instruction touches 64 distinct
//          64B lines; L2-request-bound, ~250us hidden in "aux"). Now one
//          float4/thread, lane-contiguous (lane i <-> base+16i). Grid 52096.
//      Retained: Aa[4][4] in regs (compile-time ks), log2e folded into x fp8,
//      C=0 first-MFMA, bias in LDS, setprio, bijective XCD swizzle, prep merge.

#define N_ROWS 4096
#define DIM    512              // elements per row == bytes per row in fp8
#define VOCAB  100000
#define NTILES 782              // ceil(100000/128)
#define VPAD   (NTILES * 128)   // 100096
#define SPLITS 32
#define TPS    25               // ceil(782/32)
#define XELEMS (N_ROWS * DIM)           // 2097152
#define WVALID ((size_t)VOCAB * DIM)    // 51200000
#define WBYTES ((size_t)VPAD * DIM)     // 51249152
#define TILEB  (128 * DIM)              // 65536 B: one 128-col V-tile of W(fp8)
#define CVT_BLOCKS 52096                // (XELEMS + WBYTES) / 4 / 256, exact

#define LOG2E 1.44269504088896340736f

typedef __attribute__((ext_vector_type(4))) int   i32x4;
typedef __attribute__((ext_vector_type(8))) int   i32x8;
typedef __attribute__((ext_vector_type(4))) float f32x4;

// ---------------- helpers ----------------

__device__ __forceinline__ void gload_lds16(const char* g, char* l) {
  // async global->LDS, 16B/lane; LDS dest = wave-uniform base + lane*16
  __builtin_amdgcn_global_load_lds(
      (const __attribute__((address_space(1))) unsigned int*)g,
      (__attribute__((address_space(3))) unsigned int*)l, 16, 0, 0);
}

__device__ __forceinline__ int pack4_fp8(float4 f, float sc) {
  int p = __builtin_amdgcn_cvt_pk_fp8_f32(f.x * sc, f.y * sc, 0, false);
  p = __builtin_amdgcn_cvt_pk_fp8_f32(f.z * sc, f.w * sc, p, true);
  return p;
}

// read one 32B fragment stored fragment-order: lo at base, hi at base+1024
__device__ __forceinline__ i32x8 frag32(const char* base) {
  i32x4 lo = *(const i32x4*)(base);
  i32x4 hi = *(const i32x4*)(base + 1024);
  return (i32x8){lo.x, lo.y, lo.z, lo.w, hi.x, hi.y, hi.z, hi.w};
}

// ---------------- prep: fused cvt (x*log2e, W*32 -> fp8) + exact fp32 tgt ----------------

__global__ __launch_bounds__(256) void prep_kernel(const float* __restrict__ x,
                                                   const float* __restrict__ W,
                                                   char* __restrict__ out8,
                                                   const int* __restrict__ lb,
                                                   const float* __restrict__ bias,
                                                   float* __restrict__ tgt) {
  if (blockIdx.x < CVT_BLOCKS) {
    // ---- cvt: one float4 per thread, LANE-CONTIGUOUS (lane i reads base+16i).
    // float index f0 == byte index into out8 (1 B per element).
    const size_t f0 = ((size_t)blockIdx.x * 256 + threadIdx.x) * 4;
    int o;
    if (f0 < (size_t)XELEMS) {
      // x pre-scaled by log2(e): GEMM yields logits*log2e -> epilogue raw exp2.
      o = pack4_fp8(*(const float4*)(x + f0), LOG2E);
    } else if (f0 - XELEMS < WVALID) {
      o = pack4_fp8(*(const float4*)(W + (f0 - XELEMS)), 32.f);
    } else {
      o = 0;   // vocab pad rows (also masked via -inf bias in lse)
    }
    *(int*)(out8 + f0) = o;
  } else {
    // ---- tgt part: 1024 blocks x 4 waves -> 4096 rows; exact fp32 dot
    const int wv = threadIdx.x >> 6;
    const int lane = threadIdx.x & 63;
    const int row = (blockIdx.x - CVT_BLOCKS) * 4 + wv;
    const int t = lb[row];
    const float* xr = x + (size_t)row * DIM;
    const float* wr = W + (size_t)t * DIM;
    float s = 0.f;
#pragma unroll
    for (int i = 0; i < 8; ++i) s += xr[lane + i * 64] * wr[lane + i * 64];
#pragma unroll
    for (int m = 32; m; m >>= 1) s += __shfl_xor(s, m);
    if (lane == 0) tgt[row] = s + bias[t];
  }
}

// ---------------- fused MX-fp8 GEMM + sum-exp ----------------
// grid: 1024 = 32 m-tiles x 32 V-splits. block: 4 waves = 2 row-halves (rh) x
// 2 col-halves (ch). Wave owns 64 rows (4 frags of 16) x 64 cols (4 groups of
// 16). K=128 MFMA, 4 K-steps over D=512.
// A frag (regs, 128 VGPR): lane(fr,fq) = row fr, k-bytes fq*32..+31 per K-window.
// Wave-private B LDS: 2 buffers x 8KB; buffer = ks&1; group gg (0..3 = global
// group 4ch+gg) at gg*2048; slot half*1024 + lane*16 = row 16(4ch+gg)+fr,
// k-bytes fq*32+half*16..+15. Staged by the SAME wave that reads it -> no
// cross-wave hazards, no barriers. Depth-2 counted pipeline per wave:
//   K-step u: WAITV(8) [stage(u) landed, stage(u+1) in flight] ->
//   {frag32(gg); 4 MFMA} x4 (one B-frag live at a time: spill-safe) ->
//   lgkmcnt(0) [reads done] -> stage(u+2) into the just-freed buffer.
// Scales: A identity (127, log2e folded into x fp8); B 2^-5 (122).

__global__ __launch_bounds__(256, 2) void lse_kernel(const char* __restrict__ xb,
                                                     const char* __restrict__ wb,
                                                     const float* __restrict__ bias,
                                                     float* __restrict__ spart) {
  __shared__ __align__(16) char ldsB[4][2][8192];   // [wave][buf] 64KB total
  __shared__ float ldsBias[TPS * 128];              // 12.8KB bias (log2e-scaled)

  // Bijective XCD swizzle: one XCD's co-resident blocks cover splits {2x,2x+1}
  // x all 32 m-tiles -> W slices (3.2MB) fit the 4MB per-XCD L2.
  const int d = blockIdx.x;
  const int s     = 2 * (d & 7) + ((d >> 3) & 1) + 16 * (d >> 9);
  const int mtile = (d >> 4) & 31;

  const int m0 = mtile * 128;
  const int t0 = s * TPS;
  const int t1 = (t0 + TPS < NTILES) ? (t0 + TPS) : NTILES;
  const int NT = t1 - t0;                 // 25, or 7 on the last split

  const int tid  = threadIdx.x;
  const int lane = tid & 63;
  const int wv   = tid >> 6;
  const int rh   = wv >> 1;          // row-half (64 rows)
  const int ch   = wv & 1;           // col-half (4 of the 8 col-groups)
  const int fr   = lane & 15;        // frag row (A) / col (B,C); staging row-in-group
  const int fq   = lane >> 4;        // frag quad; staging k-chunk

  // ---- load A fragments into registers (128 VGPRs): 4 row-frags x 4 ksteps ----
  i32x8 Aa[4][4];
  {
    const char* ax = xb + (size_t)(m0 + 64 * rh + fr) * DIM + fq * 32;
#pragma unroll
    for (int rf = 0; rf < 4; ++rf)
#pragma unroll
      for (int ks = 0; ks < 4; ++ks) {
        const char* p = ax + rf * (16 * DIM) + ks * 128;
        i32x4 lo = *(const i32x4*)p;
        i32x4 hi = *(const i32x4*)(p + 16);
        Aa[rf][ks] = (i32x8){lo.x, lo.y, lo.z, lo.w, hi.x, hi.y, hi.z, hi.w};
      }
  }

  // ---- stage this split's bias into LDS ----
  for (int c = tid; c < NT * 128; c += 256) {
    const int col = t0 * 128 + c;
    ldsBias[c] = (col < VOCAB) ? bias[col] * LOG2E : -INFINITY;
  }
  __syncthreads();                                   // bias visible; full drain
  asm volatile("s_waitcnt vmcnt(0)" ::: "memory");   // counted-math clean slate
  __builtin_amdgcn_sched_barrier(0);

  // wave-private staging: this wave's 4 col-groups (global 4ch..4ch+3), 8 gloads
  char* const myB  = &ldsB[wv][0][0];
  char* const buf0 = myB;
  char* const buf1 = myB + 8192;
  const size_t rowBase = (size_t)(64 * ch + fr) * DIM + fq * 32;

  auto stageK = [&](const char* tileSrc, int ks, char* dst) {
#pragma unroll
    for (int gg = 0; gg < 4; ++gg) {
      const char* src = tileSrc + rowBase + (size_t)(16 * gg) * DIM + ks * 128;
      gload_lds16(src,      dst + gg * 2048);
      gload_lds16(src + 16, dst + gg * 2048 + 1024);
    }
  };

  float S[4][4];
#pragma unroll
  for (int rf = 0; rf < 4; ++rf)
#pragma unroll
    for (int r = 0; r < 4; ++r) S[rf][r] = 0.f;

  f32x4 acc[4][4];   // [row-frag][col-frag]; C=0 at each tile's ks0

// one K-step: wait own stage(u); {read 1 frag, 4 MFMA} x4; WAR-fence; stage(u+2)
#define K_STEP(ksC, FIRSTF, WAITIMM, STAGE_EXPR)                              \
  {                                                                           \
    asm volatile("s_waitcnt vmcnt(" #WAITIMM ")" ::: "memory");               \
    __builtin_amdgcn_sched_barrier(0);                                        \
    const char* fb_ = myB + ((ksC) & 1) * 8192 + lane * 16;                   \
    __builtin_amdgcn_s_setprio(1);                                            \
    _Pragma("unroll")                                                         \
    for (int gg_ = 0; gg_ < 4; ++gg_) {                                       \
      const i32x8 bf_ = frag32(fb_ + gg_ * 2048);                             \
      _Pragma("unroll")                                                       \
      for (int rf_ = 0; rf_ < 4; ++rf_)                                       \
        acc[rf_][gg_] = __builtin_amdgcn_mfma_scale_f32_16x16x128_f8f6f4(     \
            Aa[rf_][ksC], bf_,                                                \
            (FIRSTF) ? (f32x4){0.f, 0.f, 0.f, 0.f} : acc[rf_][gg_],           \
            0, 0, 0, 127, 0, 122);                                            \
    }                                                                         \
    __builtin_amdgcn_s_setprio(0);                                            \
    asm volatile("s_waitcnt lgkmcnt(0)" ::: "memory");                        \
    __builtin_amdgcn_sched_barrier(0);                                        \
    STAGE_EXPR;                                                               \
  }

  auto epilogue = [&](int ti) {
    // C/D (16x16): col = (t0+ti)*128 + 64ch + 16c + fr, row = m0+64rh+16rf+4fq+r
    const float* bT = &ldsBias[ti * 128 + 64 * ch];
    float badd[4];
#pragma unroll
    for (int c = 0; c < 4; ++c) badd[c] = bT[16 * c + fr];
#pragma unroll
    for (int rf = 0; rf < 4; ++rf)
#pragma unroll
      for (int r = 0; r < 4; ++r) {
        float sum = 0.f;
#pragma unroll
        for (int c = 0; c < 4; ++c)
          sum += __builtin_amdgcn_exp2f(acc[rf][c][r] + badd[c]);
        S[rf][r] += sum;
      }
  };

  const char* wt = wb + (size_t)t0 * TILEB;

  // prologue: K-steps 0,1 of tile t0 in flight (16 loads outstanding)
  stageK(wt, 0, buf0);
  stageK(wt, 1, buf1);

  for (int tt = t0; tt < t1 - 1; ++tt, wt += TILEB) {
    K_STEP(0, true,  8, stageK(wt, 2, buf0))
    K_STEP(1, false, 8, stageK(wt, 3, buf1))
    K_STEP(2, false, 8, stageK(wt + TILEB, 0, buf0))
    K_STEP(3, false, 8, stageK(wt + TILEB, 1, buf1))
    epilogue(tt - t0);   // free-running: no barrier; other waves keep pipes fed
  }

  // last tile: no next-tile stages; waits 8,8,8,0
  {
    K_STEP(0, true,  8, stageK(wt, 2, buf0))
    K_STEP(1, false, 8, stageK(wt, 3, buf1))
    K_STEP(2, false, 8, (void)0)
    K_STEP(3, false, 0, (void)0)
    epilogue(NT - 1);
  }
#undef K_STEP

  // ---- cross-wave (col-half) reduction: ch=1 dumps S, ch=0 accumulates ----
  __syncthreads();                       // first barrier since bias; ldsB free
  float* sc = (float*)ldsB;              // stride 20 floats: bank-spread, x4-aligned
  if (ch == 1) {
    float* base = sc + (size_t)(rh * 64 + lane) * 20;
#pragma unroll
    for (int rf = 0; rf < 4; ++rf)
      *(float4*)(base + rf * 4) = (float4){S[rf][0], S[rf][1], S[rf][2], S[rf][3]};
  }
  __syncthreads();
  if (ch == 0) {
    const float* base = sc + (size_t)(rh * 64 + lane) * 20;
#pragma unroll
    for (int rf = 0; rf < 4; ++rf) {
      const float4 v = *(const float4*)(base + rf * 4);
      S[rf][0] += v.x; S[rf][1] += v.y; S[rf][2] += v.z; S[rf][3] += v.w;
    }
    // reduce over the 16 fr-lanes sharing each row, write partials
#pragma unroll
    for (int rf = 0; rf < 4; ++rf)
#pragma unroll
      for (int r = 0; r < 4; ++r) {
        float v = S[rf][r];
        v += __shfl_xor(v, 1);
        v += __shfl_xor(v, 2);
        v += __shfl_xor(v, 4);
        v += __shfl_xor(v, 8);
        if (fr == 0) {
          const int row = m0 + 64 * rh + 16 * rf + 4 * fq + r;
          spart[(size_t)row * SPLITS + s] = v;
        }
      }
  }
}

// ---------------- combine: loss = mean(log(sum_s S_part) - tgt), single block ----------------

__global__ __launch_bounds__(256) void combine_kernel(const float* __restrict__ spart,
                                                      const float* __restrict__ tgt,
                                                      float* __restrict__ out) {
  __shared__ float red[256];
  float local = 0.f;
  for (int r = threadIdx.x; r < N_ROWS; r += 256) {
    const float4* sp = (const float4*)(spart + (size_t)r * SPLITS);
    float st = 0.f;
#pragma unroll
    for (int i = 0; i < 8; ++i) { float4 v = sp[i]; st += (v.x + v.y) + (v.z + v.w); }
    local += __logf(st) - tgt[r];
  }
  red[threadIdx.x] = local;
  __syncthreads();
  for (int step = 128; step; step >>= 1) {
    if (threadIdx.x < step) red[threadIdx.x] += red[threadIdx.x + step];
    __syncthreads();
  }
  if (threadIdx.x == 0) out[0] = red[0] * (1.0f / (float)N_ROWS);
}

// ---------------- launch ----------------
// ws: x_fp8 [4096][512]B @0 | W_fp8 [100096][512]B | S_part [4096][32] f32 | tgt [4096] f32

extern "C" void kernel_launch(void* const* d_in, const int* in_sizes, int n_in,
                              void* d_out, int out_size, void* d_ws, size_t ws_size,
                              hipStream_t stream) {
  const float* x  = (const float*)d_in[0];
  const int*   lb = (const int*)d_in[1];
  const float* W  = (const float*)d_in[2];
  const float* b  = (const float*)d_in[3];
  float* out = (float*)d_out;

  char* ws = (char*)d_ws;
  const size_t OFF_W   = (size_t)XELEMS;          // 2097152
  const size_t OFF_SP  = OFF_W + WBYTES;          // 53346304
  const size_t OFF_TGT = OFF_SP + (size_t)N_ROWS * SPLITS * 4;
  char*  xb    = ws;
  char*  wb    = ws + OFF_W;
  float* spart = (float*)(ws + OFF_SP);
  float* tgt   = (float*)(ws + OFF_TGT);

  prep_kernel<<<CVT_BLOCKS + 1024, 256, 0, stream>>>(x, W, ws, lb, b, tgt);
  lse_kernel<<<1024, 256, 0, stream>>>(xb, wb, b, spart);
  combine_kernel<<<1, 256, 0, stream>>>(spart, tgt, out);
}

// Round 6
// 496.089 us; speedup vs baseline: 1.5723x; 1.3564x over previous
//
#include <hip/hip_runtime.h>
#include <hip/hip_bf16.h>
#include <math.h>

// ModelParallelSoftmaxLoss: loss = mean(logsumexp(x@W^T + b) - (x@W^T+b)[lb])
// N=4096, D=512, V=100000.
// R12: staging-coalescing fix. R11 wall = 2460 cy/block-K-step ~= 2048 global
//      line-requests/CU-K-step: each gload was a 512B-row-stride gather (16
//      rows x 2 lines = 32 lines per 1KB instruction, 2x the 16-line minimum).
//      Fix per rule #21 (linear LDS dest + permuted global src + permuted read):
//      per-group 2KB layout off(r,q) = r*128 + (q^(r&7))*16  (r=row 0..15,
//      q=16B granule 0..7 of the 128B K-window). Then:
//        stage  : dest linear h*1024+16l; src lane-const offset
//                 (l>>3)*512 + ((l&7)^((l>>3)&7))*16  -> each 8-lane cluster
//                 reads one row's 128B window contiguously = 16 lines/gload.
//        read   : lane-const loOff=(l&15)*128+((2(l>>4))^(l&7))*16, hiOff=+1^;
//                 granule classes spread 8 lanes/4-bank group = b128 optimum.
//      Everything else unchanged from R11: barrier-free wave-private pipeline
//      (depth-2, WAITV(8), lgkmcnt(0) WAR fence), Aa[4][4] regs, log2e in x,
//      C=0 first-MFMA, bias in LDS, setprio, bijective XCD swizzle.

#define N_ROWS 4096
#define DIM    512              // elements per row == bytes per row in fp8
#define VOCAB  100000
#define NTILES 782              // ceil(100000/128)
#define VPAD   (NTILES * 128)   // 100096
#define SPLITS 32
#define TPS    25               // ceil(782/32)
#define XELEMS (N_ROWS * DIM)           // 2097152
#define WVALID ((size_t)VOCAB * DIM)    // 51200000
#define WBYTES ((size_t)VPAD * DIM)     // 51249152
#define TILEB  (128 * DIM)              // 65536 B: one 128-col V-tile of W(fp8)
#define CVT_BLOCKS 52096                // (XELEMS + WBYTES) / 4 / 256, exact

#define LOG2E 1.44269504088896340736f

typedef __attribute__((ext_vector_type(4))) int   i32x4;
typedef __attribute__((ext_vector_type(8))) int   i32x8;
typedef __attribute__((ext_vector_type(4))) float f32x4;

// ---------------- helpers ----------------

__device__ __forceinline__ void gload_lds16(const char* g, char* l) {
  // async global->LDS, 16B/lane; LDS dest = wave-uniform base + lane*16
  __builtin_amdgcn_global_load_lds(
      (const __attribute__((address_space(1))) unsigned int*)g,
      (__attribute__((address_space(3))) unsigned int*)l, 16, 0, 0);
}

__device__ __forceinline__ int pack4_fp8(float4 f, float sc) {
  int p = __builtin_amdgcn_cvt_pk_fp8_f32(f.x * sc, f.y * sc, 0, false);
  p = __builtin_amdgcn_cvt_pk_fp8_f32(f.z * sc, f.w * sc, p, true);
  return p;
}

// ---------------- prep: fused cvt (x*log2e, W*32 -> fp8) + exact fp32 tgt ----------------

__global__ __launch_bounds__(256) void prep_kernel(const float* __restrict__ x,
                                                   const float* __restrict__ W,
                                                   char* __restrict__ out8,
                                                   const int* __restrict__ lb,
                                                   const float* __restrict__ bias,
                                                   float* __restrict__ tgt) {
  if (blockIdx.x < CVT_BLOCKS) {
    // ---- cvt: one float4 per thread, lane-contiguous
    const size_t f0 = ((size_t)blockIdx.x * 256 + threadIdx.x) * 4;
    int o;
    if (f0 < (size_t)XELEMS) {
      // x pre-scaled by log2(e): GEMM yields logits*log2e -> epilogue raw exp2.
      o = pack4_fp8(*(const float4*)(x + f0), LOG2E);
    } else if (f0 - XELEMS < WVALID) {
      o = pack4_fp8(*(const float4*)(W + (f0 - XELEMS)), 32.f);
    } else {
      o = 0;   // vocab pad rows (also masked via -inf bias in lse)
    }
    *(int*)(out8 + f0) = o;
  } else {
    // ---- tgt part: 1024 blocks x 4 waves -> 4096 rows; exact fp32 dot
    const int wv = threadIdx.x >> 6;
    const int lane = threadIdx.x & 63;
    const int row = (blockIdx.x - CVT_BLOCKS) * 4 + wv;
    const int t = lb[row];
    const float* xr = x + (size_t)row * DIM;
    const float* wr = W + (size_t)t * DIM;
    float s = 0.f;
#pragma unroll
    for (int i = 0; i < 8; ++i) s += xr[lane + i * 64] * wr[lane + i * 64];
#pragma unroll
    for (int m = 32; m; m >>= 1) s += __shfl_xor(s, m);
    if (lane == 0) tgt[row] = s + bias[t];
  }
}

// ---------------- fused MX-fp8 GEMM + sum-exp ----------------
// grid: 1024 = 32 m-tiles x 32 V-splits. block: 4 waves = 2 row-halves (rh) x
// 2 col-halves (ch). Wave owns 64 rows (4 frags of 16) x 64 cols (4 groups of
// 16). K=128 MFMA, 4 K-steps over D=512.
// A frag (regs, 128 VGPR): lane(fr,fq) = row fr, k-bytes fq*32..+31 per K-window.
// Wave-private B LDS: 2 buffers x 8KB; buffer = ks&1; group gg (0..3 = global
// group 4ch+gg) at gg*2048. Group block layout (R12): data(row r, granule q)
// at r*128 + (q^(r&7))*16. Staged by the SAME wave that reads it -> no
// cross-wave hazards, no barriers. Depth-2 counted pipeline per wave:
//   K-step u: WAITV(8) [stage(u) landed, stage(u+1) in flight] ->
//   {read 1 frag via lo/hi 16B, 4 MFMA} x4 (one B-frag live at a time) ->
//   lgkmcnt(0) [reads done] -> stage(u+2) into the just-freed buffer.
// Scales: A identity (127, log2e folded into x fp8); B 2^-5 (122).

__global__ __launch_bounds__(256, 2) void lse_kernel(const char* __restrict__ xb,
                                                     const char* __restrict__ wb,
                                                     const float* __restrict__ bias,
                                                     float* __restrict__ spart) {
  __shared__ __align__(16) char ldsB[4][2][8192];   // [wave][buf] 64KB total
  __shared__ float ldsBias[TPS * 128];              // 12.8KB bias (log2e-scaled)

  // Bijective XCD swizzle: one XCD's co-resident blocks cover splits {2x,2x+1}
  // x all 32 m-tiles -> W slices (3.2MB) fit the 4MB per-XCD L2.
  const int d = blockIdx.x;
  const int s     = 2 * (d & 7) + ((d >> 3) & 1) + 16 * (d >> 9);
  const int mtile = (d >> 4) & 31;

  const int m0 = mtile * 128;
  const int t0 = s * TPS;
  const int t1 = (t0 + TPS < NTILES) ? (t0 + TPS) : NTILES;
  const int NT = t1 - t0;                 // 25, or 7 on the last split

  const int tid  = threadIdx.x;
  const int lane = tid & 63;
  const int wv   = tid >> 6;
  const int rh   = wv >> 1;          // row-half (64 rows)
  const int ch   = wv & 1;           // col-half (4 of the 8 col-groups)
  const int fr   = lane & 15;        // frag row (A) / col (B,C)
  const int fq   = lane >> 4;        // frag quad

  // ---- R12 lane-constant staging/read offsets (see layout comment) ----
  // stage source: lane l fetches (row l>>3, granule (l&7)^((l>>3)&7)) of the
  // 128B window -> each 8-lane cluster reads one row's window contiguously.
  const int stSrcOff = ((lane >> 3) * DIM) + ((((lane & 7) ^ ((lane >> 3) & 7))) << 4);
  // frag read: lane l wants (row fr, granules 2fq, 2fq+1), stored swizzled.
  const int loOff = (fr << 7) + (((2 * fq)     ^ (lane & 7)) << 4);
  const int hiOff = (fr << 7) + (((2 * fq + 1) ^ (lane & 7)) << 4);

  // ---- load A fragments into registers (128 VGPRs): 4 row-frags x 4 ksteps ----
  i32x8 Aa[4][4];
  {
    const char* ax = xb + (size_t)(m0 + 64 * rh + fr) * DIM + fq * 32;
#pragma unroll
    for (int rf = 0; rf < 4; ++rf)
#pragma unroll
      for (int ks = 0; ks < 4; ++ks) {
        const char* p = ax + rf * (16 * DIM) + ks * 128;
        i32x4 lo = *(const i32x4*)p;
        i32x4 hi = *(const i32x4*)(p + 16);
        Aa[rf][ks] = (i32x8){lo.x, lo.y, lo.z, lo.w, hi.x, hi.y, hi.z, hi.w};
      }
  }

  // ---- stage this split's bias into LDS ----
  for (int c = tid; c < NT * 128; c += 256) {
    const int col = t0 * 128 + c;
    ldsBias[c] = (col < VOCAB) ? bias[col] * LOG2E : -INFINITY;
  }
  __syncthreads();                                   // bias visible; full drain
  asm volatile("s_waitcnt vmcnt(0)" ::: "memory");   // counted-math clean slate
  __builtin_amdgcn_sched_barrier(0);

  // wave-private staging: this wave's 4 col-groups (global 4ch..4ch+3), 8 gloads
  char* const myB  = &ldsB[wv][0][0];
  char* const buf0 = myB;
  char* const buf1 = myB + 8192;

  // stage K-step ks of tile tileSrc into dst (8 gloads, 16 lines each)
  auto stageK = [&](const char* tileSrc, int ks, char* dst) {
    const char* base = tileSrc + (size_t)(64 * ch) * DIM + ks * 128 + stSrcOff;
#pragma unroll
    for (int gg = 0; gg < 4; ++gg) {
      gload_lds16(base + (size_t)(16 * gg) * DIM,             dst + gg * 2048);
      gload_lds16(base + (size_t)(16 * gg + 8) * DIM,         dst + gg * 2048 + 1024);
    }
  };

  float S[4][4];
#pragma unroll
  for (int rf = 0; rf < 4; ++rf)
#pragma unroll
    for (int r = 0; r < 4; ++r) S[rf][r] = 0.f;

  f32x4 acc[4][4];   // [row-frag][col-frag]; C=0 at each tile's ks0

// one K-step: wait own stage(u); {read 1 frag (lo/hi swizzled), 4 MFMA} x4;
// WAR-fence; stage(u+2)
#define K_STEP(ksC, FIRSTF, WAITIMM, STAGE_EXPR)                              \
  {                                                                           \
    asm volatile("s_waitcnt vmcnt(" #WAITIMM ")" ::: "memory");               \
    __builtin_amdgcn_sched_barrier(0);                                        \
    const char* fb_ = myB + ((ksC) & 1) * 8192;                               \
    __builtin_amdgcn_s_setprio(1);                                            \
    _Pragma("unroll")                                                         \
    for (int gg_ = 0; gg_ < 4; ++gg_) {                                       \
      const char* p_ = fb_ + gg_ * 2048;                                      \
      const i32x4 lo_ = *(const i32x4*)(p_ + loOff);                          \
      const i32x4 hi_ = *(const i32x4*)(p_ + hiOff);                          \
      const i32x8 bf_ = (i32x8){lo_.x, lo_.y, lo_.z, lo_.w,                   \
                                hi_.x, hi_.y, hi_.z, hi_.w};                  \
      _Pragma("unroll")                                                       \
      for (int rf_ = 0; rf_ < 4; ++rf_)                                       \
        acc[rf_][gg_] = __builtin_amdgcn_mfma_scale_f32_16x16x128_f8f6f4(     \
            Aa[rf_][ksC], bf_,                                                \
            (FIRSTF) ? (f32x4){0.f, 0.f, 0.f, 0.f} : acc[rf_][gg_],           \
            0, 0, 0, 127, 0, 122);                                            \
    }                                                                         \
    __builtin_amdgcn_s_setprio(0);                                            \
    asm volatile("s_waitcnt lgkmcnt(0)" ::: "memory");                        \
    __builtin_amdgcn_sched_barrier(0);                                        \
    STAGE_EXPR;                                                               \
  }

  auto epilogue = [&](int ti) {
    // C/D (16x16): col = (t0+ti)*128 + 64ch + 16c + fr, row = m0+64rh+16rf+4fq+r
    const float* bT = &ldsBias[ti * 128 + 64 * ch];
    float badd[4];
#pragma unroll
    for (int c = 0; c < 4; ++c) badd[c] = bT[16 * c + fr];
#pragma unroll
    for (int rf = 0; rf < 4; ++rf)
#pragma unroll
      for (int r = 0; r < 4; ++r) {
        float sum = 0.f;
#pragma unroll
        for (int c = 0; c < 4; ++c)
          sum += __builtin_amdgcn_exp2f(acc[rf][c][r] + badd[c]);
        S[rf][r] += sum;
      }
  };

  const char* wt = wb + (size_t)t0 * TILEB;

  // prologue: K-steps 0,1 of tile t0 in flight (16 loads outstanding)
  stageK(wt, 0, buf0);
  stageK(wt, 1, buf1);

  for (int tt = t0; tt < t1 - 1; ++tt, wt += TILEB) {
    K_STEP(0, true,  8, stageK(wt, 2, buf0))
    K_STEP(1, false, 8, stageK(wt, 3, buf1))
    K_STEP(2, false, 8, stageK(wt + TILEB, 0, buf0))
    K_STEP(3, false, 8, stageK(wt + TILEB, 1, buf1))
    epilogue(tt - t0);   // free-running: no barrier; other waves keep pipes fed
  }

  // last tile: no next-tile stages; waits 8,8,8,0
  {
    K_STEP(0, true,  8, stageK(wt, 2, buf0))
    K_STEP(1, false, 8, stageK(wt, 3, buf1))
    K_STEP(2, false, 8, (void)0)
    K_STEP(3, false, 0, (void)0)
    epilogue(NT - 1);
  }
#undef K_STEP

  // ---- cross-wave (col-half) reduction: ch=1 dumps S, ch=0 accumulates ----
  __syncthreads();                       // first barrier since bias; ldsB free
  float* sc = (float*)ldsB;              // stride 20 floats: bank-spread, x4-aligned
  if (ch == 1) {
    float* base = sc + (size_t)(rh * 64 + lane) * 20;
#pragma unroll
    for (int rf = 0; rf < 4; ++rf)
      *(float4*)(base + rf * 4) = (float4){S[rf][0], S[rf][1], S[rf][2], S[rf][3]};
  }
  __syncthreads();
  if (ch == 0) {
    const float* base = sc + (size_t)(rh * 64 + lane) * 20;
#pragma unroll
    for (int rf = 0; rf < 4; ++rf) {
      const float4 v = *(const float4*)(base + rf * 4);
      S[rf][0] += v.x; S[rf][1] += v.y; S[rf][2] += v.z; S[rf][3] += v.w;
    }
    // reduce over the 16 fr-lanes sharing each row, write partials
#pragma unroll
    for (int rf = 0; rf < 4; ++rf)
#pragma unroll
      for (int r = 0; r < 4; ++r) {
        float v = S[rf][r];
        v += __shfl_xor(v, 1);
        v += __shfl_xor(v, 2);
        v += __shfl_xor(v, 4);
        v += __shfl_xor(v, 8);
        if (fr == 0) {
          const int row = m0 + 64 * rh + 16 * rf + 4 * fq + r;
          spart[(size_t)row * SPLITS + s] = v;
        }
      }
  }
}

// ---------------- combine: loss = mean(log(sum_s S_part) - tgt), single block ----------------

__global__ __launch_bounds__(256) void combine_kernel(const float* __restrict__ spart,
                                                      const float* __restrict__ tgt,
                                                      float* __restrict__ out) {
  __shared__ float red[256];
  float local = 0.f;
  for (int r = threadIdx.x; r < N_ROWS; r += 256) {
    const float4* sp = (const float4*)(spart + (size_t)r * SPLITS);
    float st = 0.f;
#pragma unroll
    for (int i = 0; i < 8; ++i) { float4 v = sp[i]; st += (v.x + v.y) + (v.z + v.w); }
    local += __logf(st) - tgt[r];
  }
  red[threadIdx.x] = local;
  __syncthreads();
  for (int step = 128; step; step >>= 1) {
    if (threadIdx.x < step) red[threadIdx.x] += red[threadIdx.x + step];
    __syncthreads();
  }
  if (threadIdx.x == 0) out[0] = red[0] * (1.0f / (float)N_ROWS);
}

// ---------------- launch ----------------
// ws: x_fp8 [4096][512]B @0 | W_fp8 [100096][512]B | S_part [4096][32] f32 | tgt [4096] f32

extern "C" void kernel_launch(void* const* d_in, const int* in_sizes, int n_in,
                              void* d_out, int out_size, void* d_ws, size_t ws_size,
                              hipStream_t stream) {
  const float* x  = (const float*)d_in[0];
  const int*   lb = (const int*)d_in[1];
  const float* W  = (const float*)d_in[2];
  const float* b  = (const float*)d_in[3];
  float* out = (float*)d_out;

  char* ws = (char*)d_ws;
  const size_t OFF_W   = (size_t)XELEMS;          // 2097152
  const size_t OFF_SP  = OFF_W + WBYTES;          // 53346304
  const size_t OFF_TGT = OFF_SP + (size_t)N_ROWS * SPLITS * 4;
  char*  xb    = ws;
  char*  wb    = ws + OFF_W;
  float* spart = (float*)(ws + OFF_SP);
  float* tgt   = (float*)(ws + OFF_TGT);

  prep_kernel<<<CVT_BLOCKS + 1024, 256, 0, stream>>>(x, W, ws, lb, b, tgt);
  lse_kernel<<<1024, 256, 0, stream>>>(xb, wb, b, spart);
  combine_kernel<<<1, 256, 0, stream>>>(spart, tgt, out);
}